// Round 13
// baseline (154.423 us; speedup 1.0000x reference)
//
#include <hip/hip_runtime.h>
#include <hip/hip_bf16.h>
#include <math.h>

typedef __bf16 bf16x8 __attribute__((ext_vector_type(8)));
typedef float f32x4 __attribute__((ext_vector_type(4)));
typedef float f32x2 __attribute__((ext_vector_type(2)));

__device__ __forceinline__ float lrelu(float x) { return x > 0.f ? x : 0.2f * x; }
__device__ __forceinline__ unsigned short f2bf(float f) {
    unsigned u = __float_as_uint(f);
    return (unsigned short)((u + 0x7fffu + ((u >> 16) & 1u)) >> 16);
}
__device__ __forceinline__ float bf16lo(unsigned u) { return __uint_as_float(u << 16); }
__device__ __forceinline__ float bf16hi(unsigned u) { return __uint_as_float(u & 0xffff0000u); }
__device__ __forceinline__ unsigned pkbf(float a, float b) {
    return (unsigned)f2bf(a) | ((unsigned)f2bf(b) << 16);
}
__device__ __forceinline__ float wred_sum(float v) {
#pragma unroll
    for (int o = 32; o; o >>= 1) v += __shfl_xor(v, o);
    return v;
}

// ============ CSR build: two-level bucket sort on u32-packed edges (N < 65536) ========
// packed edge = (dst << 16) | src. coarse digit = dst>>8 = packed>>24.

// k1: per-block LDS histogram; tail blocks (b >= NB) cast W1/W2 to bf16.
__global__ __launch_bounds__(256) void k1_hist(const int* __restrict__ ei, int E, int Et,
                                               int* __restrict__ g_hist, int NB,
                                               const float* __restrict__ W1,
                                               const float* __restrict__ W2,
                                               unsigned short* __restrict__ w1b,
                                               unsigned short* __restrict__ w2b) {
    int tid = threadIdx.x, b = blockIdx.x;
    if (b >= NB) {
        int i = (b - NB) * 256 + tid;   // vec8 index
        const float* src;
        unsigned short* dst;
        size_t off;
        if (i < 2048)      { src = W1; dst = w1b; off = (size_t)i * 8; }
        else if (i < 3072) { src = W2; dst = w2b; off = (size_t)(i - 2048) * 8; }
        else return;
        float4 v0 = *(const float4*)(src + off);
        float4 v1 = *(const float4*)(src + off + 4);
        union { unsigned short u[8]; uint4 q; } o;
        o.u[0] = f2bf(v0.x); o.u[1] = f2bf(v0.y); o.u[2] = f2bf(v0.z); o.u[3] = f2bf(v0.w);
        o.u[4] = f2bf(v1.x); o.u[5] = f2bf(v1.y); o.u[6] = f2bf(v1.z); o.u[7] = f2bf(v1.w);
        *(uint4*)(dst + off) = o.q;
        return;
    }
    __shared__ int hist[256];
    hist[tid] = 0;
    __syncthreads();
    int base = b * 4096;
#pragma unroll
    for (int k = 0; k < 16; ++k) {
        int e = base + k * 256 + tid;
        if (e < Et) {
            int d = (e < E) ? ei[E + e] : (e - E);
            atomicAdd(&hist[d >> 8], 1);
        }
    }
    __syncthreads();
    g_hist[tid * NB + b] = hist[tid];
}

__global__ __launch_bounds__(256) void scan_p1(const int* __restrict__ in,
                                               int* __restrict__ partial, int n) {
    __shared__ int ws[4];
    int tid = threadIdx.x, lane = tid & 63, w = tid >> 6;
    int idx = blockIdx.x * 256 + tid;
    int v = (idx < n) ? in[idx] : 0;
    int s = v;
#pragma unroll
    for (int o = 32; o; o >>= 1) s += __shfl_xor(s, o);
    if (lane == 0) ws[w] = s;
    __syncthreads();
    if (tid == 0) partial[blockIdx.x] = ws[0] + ws[1] + ws[2] + ws[3];
}

__global__ __launch_bounds__(256) void scan_p2(int* __restrict__ partial, int nb) {
    __shared__ int ws[4];
    __shared__ int s_carry;
    int tid = threadIdx.x, lane = tid & 63, w = tid >> 6;
    if (tid == 0) s_carry = 0;
    __syncthreads();
    for (int base = 0; base < nb; base += 256) {
        int idx = base + tid;
        int v = (idx < nb) ? partial[idx] : 0;
        int incl = v;
#pragma unroll
        for (int off = 1; off < 64; off <<= 1) {
            int t = __shfl_up(incl, off);
            if (lane >= off) incl += t;
        }
        if (lane == 63) ws[w] = incl;
        __syncthreads();
        int wpre = 0;
        for (int k = 0; k < w; ++k) wpre += ws[k];
        int carry = s_carry;
        if (idx < nb) partial[idx] = carry + wpre + incl - v;
        __syncthreads();
        if (tid == 255) s_carry = carry + wpre + incl;
        __syncthreads();
    }
}

__global__ __launch_bounds__(256) void scan_p3g(const int* __restrict__ in,
                                                const int* __restrict__ partial,
                                                int* __restrict__ out, int n) {
    __shared__ int ws[4];
    int tid = threadIdx.x, lane = tid & 63, w = tid >> 6;
    int idx = blockIdx.x * 256 + tid;
    int v = (idx < n) ? in[idx] : 0;
    int incl = v;
#pragma unroll
    for (int off = 1; off < 64; off <<= 1) {
        int t = __shfl_up(incl, off);
        if (lane >= off) incl += t;
    }
    if (lane == 63) ws[w] = incl;
    __syncthreads();
    int wpre = 0;
    for (int k = 0; k < w; ++k) wpre += ws[k];
    if (idx < n) out[idx] = partial[blockIdx.x] + wpre + incl - v;
    if (idx == n - 1) out[n] = partial[blockIdx.x] + wpre + incl;
}

__global__ __launch_bounds__(256) void k3_scatter(const int* __restrict__ ei, int E, int Et,
                                                  const int* __restrict__ g_scan,
                                                  unsigned* __restrict__ tmp, int NB) {
    __shared__ int hist[256], lofs[256], lcnt[256], gbase[256];
    __shared__ int ws4[4];
    __shared__ unsigned stage[4096];
    int tid = threadIdx.x, b = blockIdx.x;
    int lane = tid & 63, w = tid >> 6;
    int base = b * 4096;
    int valid = min(4096, Et - base);
    unsigned pv[16];
    hist[tid] = 0;
    lcnt[tid] = 0;
    gbase[tid] = g_scan[tid * NB + b];
    __syncthreads();
#pragma unroll
    for (int k = 0; k < 16; ++k) {
        int e = base + k * 256 + tid;
        if (e < Et) {
            int s, d;
            if (e < E) { s = ei[e]; d = ei[E + e]; } else { s = d = e - E; }
            pv[k] = ((unsigned)d << 16) | (unsigned)s;
            atomicAdd(&hist[d >> 8], 1);
        }
    }
    __syncthreads();
    {
        int v = hist[tid];
        int incl = v;
#pragma unroll
        for (int off = 1; off < 64; off <<= 1) {
            int t = __shfl_up(incl, off);
            if (lane >= off) incl += t;
        }
        if (lane == 63) ws4[w] = incl;
        __syncthreads();
        int wpre = 0;
        for (int k = 0; k < w; ++k) wpre += ws4[k];
        lofs[tid] = wpre + incl - v;
    }
    __syncthreads();
#pragma unroll
    for (int k = 0; k < 16; ++k) {
        int e = base + k * 256 + tid;
        if (e < Et) {
            int dg = pv[k] >> 24;
            int r = atomicAdd(&lcnt[dg], 1);
            stage[lofs[dg] + r] = pv[k];
        }
    }
    __syncthreads();
    for (int j = tid; j < valid; j += 256) {
        unsigned v = stage[j];
        int dg = v >> 24;
        tmp[gbase[dg] + (j - lofs[dg])] = v;
    }
}

__global__ __launch_bounds__(256) void csr_finalize(const unsigned* __restrict__ tmp,
                                                    const int* __restrict__ g_scan,
                                                    int* __restrict__ srcs,
                                                    int* __restrict__ rowptr,
                                                    int N, int Et, int NB) {
    __shared__ int cnt[256], lofs[256], lcnt[256];
    __shared__ int ws4[4];
    __shared__ unsigned short sstage[8192];
    int tid = threadIdx.x, g = blockIdx.x;
    int lane = tid & 63, w = tid >> 6;
    int start = g_scan[g * NB];
    int end = g_scan[(g + 1) * NB];
    int sz = end - start;
    cnt[tid] = 0;
    lcnt[tid] = 0;
    __syncthreads();
    for (int e = start + tid; e < end; e += 256)
        atomicAdd(&cnt[(tmp[e] >> 16) & 255u], 1);
    __syncthreads();
    {
        int v = cnt[tid];
        int incl = v;
#pragma unroll
        for (int off = 1; off < 64; off <<= 1) {
            int t = __shfl_up(incl, off);
            if (lane >= off) incl += t;
        }
        if (lane == 63) ws4[w] = incl;
        __syncthreads();
        int wpre = 0;
        for (int k = 0; k < w; ++k) wpre += ws4[k];
        lofs[tid] = wpre + incl - v;
    }
    __syncthreads();
    int d = g * 256 + tid;
    if (d < N) rowptr[d] = start + lofs[tid];
    if (d == N - 1) rowptr[N] = Et;
    if (sz <= 8192) {
        for (int e = start + tid; e < end; e += 256) {
            unsigned v = tmp[e];
            int sub = (v >> 16) & 255u;
            int pos = lofs[sub] + atomicAdd(&lcnt[sub], 1);
            sstage[pos] = (unsigned short)(v & 0xffffu);
        }
        __syncthreads();
        for (int j = tid; j < sz; j += 256)
            srcs[start + j] = (int)sstage[j];
    } else {
        for (int e = start + tid; e < end; e += 256) {
            unsigned v = tmp[e];
            int sub = (v >> 16) & 255u;
            int pos = start + lofs[sub] + atomicAdd(&lcnt[sub], 1);
            srcs[pos] = (int)(v & 0xffffu);
        }
    }
}

// ------- MFMA GEMM (bf16 out) + fused node_alpha; AF32 = on-the-fly f32->bf16 A ------
template<int M, int H, bool AF32>
__global__ __launch_bounds__(256) void gemm_mfma(const void* __restrict__ Av,
                                                 const unsigned short* __restrict__ Wb,
                                                 const float* __restrict__ att_s,
                                                 const float* __restrict__ att_d,
                                                 unsigned short* __restrict__ Cb,
                                                 float* __restrict__ as_,
                                                 float* __restrict__ ad_,
                                                 int N) {
    constexpr int CT = M / 16;
    int tid = threadIdx.x;
    int wid = tid >> 6, l = tid & 63;
    int l15 = l & 15, lhi = l >> 4;
    int rowbase = blockIdx.x * 64 + wid * 16;
    f32x4 acc[CT] = {};

    int rc = min(rowbase + l15, N - 1);
    const unsigned short* ap = (const unsigned short*)Av + (size_t)rc * 128 + lhi * 8;
    const float* apf = (const float*)Av + (size_t)rc * 128 + lhi * 8;
    const unsigned short* wp = Wb + (size_t)l15 * 128 + lhi * 8;

#pragma unroll
    for (int ks = 0; ks < 4; ++ks) {
        int k0 = ks * 32;
        bf16x8 a;
        if (AF32) {
            float4 u0 = *(const float4*)(apf + k0);
            float4 u1 = *(const float4*)(apf + k0 + 4);
            union { unsigned short s[8]; bf16x8 v; } cc;
            cc.s[0] = f2bf(u0.x); cc.s[1] = f2bf(u0.y); cc.s[2] = f2bf(u0.z); cc.s[3] = f2bf(u0.w);
            cc.s[4] = f2bf(u1.x); cc.s[5] = f2bf(u1.y); cc.s[6] = f2bf(u1.z); cc.s[7] = f2bf(u1.w);
            a = cc.v;
        } else {
            a = *reinterpret_cast<const bf16x8*>(ap + k0);
        }
#pragma unroll
        for (int ct = 0; ct < CT; ++ct) {
            bf16x8 b = *reinterpret_cast<const bf16x8*>(wp + (size_t)ct * 16 * 128 + k0);
            acc[ct] = __builtin_amdgcn_mfma_f32_16x16x32_bf16(a, b, acc[ct], 0, 0, 0);
        }
    }

    int rbase = rowbase + lhi * 4;
#pragma unroll
    for (int j = 0; j < 4; ++j) {
        int gr = rbase + j;
        if (gr < N) {
#pragma unroll
            for (int ct = 0; ct < CT; ++ct)
                Cb[(size_t)gr * M + ct * 16 + l15] = f2bf(acc[ct][j]);
        }
    }
#pragma unroll
    for (int hd = 0; hd < H; ++hd) {
        float ps0 = 0.f, ps1 = 0.f, ps2 = 0.f, ps3 = 0.f;
        float pd0 = 0.f, pd1 = 0.f, pd2 = 0.f, pd3 = 0.f;
#pragma unroll
        for (int c4 = 0; c4 < 4; ++c4) {
            int ct = hd * 4 + c4;
            float ws = att_s[hd * 64 + c4 * 16 + l15];
            float wd = att_d[hd * 64 + c4 * 16 + l15];
            ps0 += acc[ct][0] * ws; pd0 += acc[ct][0] * wd;
            ps1 += acc[ct][1] * ws; pd1 += acc[ct][1] * wd;
            ps2 += acc[ct][2] * ws; pd2 += acc[ct][2] * wd;
            ps3 += acc[ct][3] * ws; pd3 += acc[ct][3] * wd;
        }
#pragma unroll
        for (int o = 1; o < 16; o <<= 1) {
            ps0 += __shfl_xor(ps0, o); pd0 += __shfl_xor(pd0, o);
            ps1 += __shfl_xor(ps1, o); pd1 += __shfl_xor(pd1, o);
            ps2 += __shfl_xor(ps2, o); pd2 += __shfl_xor(pd2, o);
            ps3 += __shfl_xor(ps3, o); pd3 += __shfl_xor(pd3, o);
        }
        if (l15 == 0) {
            int gr = rbase;
            if (gr < N)     { as_[(size_t)gr * H + hd] = ps0; ad_[(size_t)gr * H + hd] = pd0; }
            if (gr + 1 < N) { as_[(size_t)(gr + 1) * H + hd] = ps1; ad_[(size_t)(gr + 1) * H + hd] = pd1; }
            if (gr + 2 < N) { as_[(size_t)(gr + 2) * H + hd] = ps2; ad_[(size_t)(gr + 2) * H + hd] = pd2; }
            if (gr + 3 < N) { as_[(size_t)(gr + 3) * H + hd] = ps3; ad_[(size_t)(gr + 3) * H + hd] = pd3; }
        }
    }
}

// ------- fused softmax + aggregation: 8 lanes/edge, 8 edges/iter, wide loads ---------
// H=2: lane covers 16 ch (2x uint4 = 32 B), bf16 out. H=1: 8 ch (1x uint4), f32 out.
template<int H, bool DO_ELU>
__global__ __launch_bounds__(256) void gat_agg(const int* __restrict__ rowptr,
                                               const int* __restrict__ srcs,
                                               const float* __restrict__ as_,
                                               const float* __restrict__ ad_,
                                               const unsigned* __restrict__ hfeat,
                                               const float* __restrict__ bias,
                                               void* __restrict__ outp, int N) {
    constexpr int RW = 32 * H;            // u32 words per feature row
    constexpr int G  = 8;                  // edges per iteration
    constexpr int NV = 4 * H;              // f32x2 accumulators per lane (8*H channels)
    __shared__ uint4 sent[4][64];
    int wid = threadIdx.x >> 6, lane = threadIdx.x & 63;
    int il = lane & 7;
    int grp = lane >> 3;
    int d = blockIdx.x * 4 + wid;
    if (d >= N) return;
    int r0 = rowptr[d], r1 = rowptr[d + 1];
    int cnt = r1 - r0;
    float uad[H];
    if (H == 2) {
        float2 adp = *(const float2*)(ad_ + 2 * (size_t)d);
        uad[0] = adp.x; uad[H - 1] = adp.y;
    } else {
        uad[0] = ad_[d];
    }
    f32x2 A[NV];
#pragma unroll
    for (int q = 0; q < NV; ++q) A[q] = f32x2{0.f, 0.f};
    const char* hflb = (const char*)hfeat + 16 * H * il;   // lane-fixed byte offset
    bool hhi = (H == 2) && (il >= 4);
    const unsigned* sbase = reinterpret_cast<const unsigned*>(&sent[wid][0]) + (hhi ? 2 : 0);

    if (cnt <= 64) {
        int i = r0 + lane;
        bool act = i < r1;
        int se = act ? srcs[i] : 0;
        float ax[H];
        if (H == 2) {
            float2 asp = *(const float2*)(as_ + 2 * (size_t)se);
            float ex0 = act ? __expf(lrelu(asp.x + uad[0])) : 0.f;
            float ex1 = act ? __expf(lrelu(asp.y + uad[1])) : 0.f;
            float den0 = wred_sum(ex0);
            float den1 = wred_sum(ex1);
            ax[0] = ex0 * __builtin_amdgcn_rcpf(den0 + 1e-16f);
            ax[H - 1] = ex1 * __builtin_amdgcn_rcpf(den1 + 1e-16f);
        } else {
            float ex = act ? __expf(lrelu(as_[se] + uad[0])) : 0.f;
            float den = wred_sum(ex);
            ax[0] = ex * __builtin_amdgcn_rcpf(den + 1e-16f);
        }
        unsigned off = (unsigned)(se * (RW * 4));
        sent[wid][lane] = make_uint4(off, __float_as_uint(ax[0]),
                                     off, __float_as_uint(ax[H - 1]));
        __threadfence_block();
#pragma unroll 2
        for (int t = 0; t < cnt; t += G) {
            uint2 en = *(const uint2*)(sbase + 4 * (t + grp));
            float af = __uint_as_float(en.y);
            const char* rowp = hflb + en.x;
            uint4 u0 = *(const uint4*)(rowp);
            f32x2 c;
            c.x = bf16lo(u0.x); c.y = bf16hi(u0.x); A[0] += af * c;
            c.x = bf16lo(u0.y); c.y = bf16hi(u0.y); A[1] += af * c;
            c.x = bf16lo(u0.z); c.y = bf16hi(u0.z); A[2] += af * c;
            c.x = bf16lo(u0.w); c.y = bf16hi(u0.w); A[3] += af * c;
            if (H == 2) {
                uint4 u1 = *(const uint4*)(rowp + 16);
                c.x = bf16lo(u1.x); c.y = bf16hi(u1.x); A[4] += af * c;
                c.x = bf16lo(u1.y); c.y = bf16hi(u1.y); A[5] += af * c;
                c.x = bf16lo(u1.z); c.y = bf16hi(u1.z); A[6] += af * c;
                c.x = bf16lo(u1.w); c.y = bf16hi(u1.w); A[7] += af * c;
            }
        }
    } else {
        // chunked path (deg > 64) -- statistically never, correctness only
        float psum[H];
#pragma unroll
        for (int h = 0; h < H; ++h) psum[h] = 0.f;
        for (int base = r0; base < r1; base += 64) {
            int i = base + lane;
            bool act = i < r1;
            int s = act ? srcs[i] : 0;
#pragma unroll
            for (int h = 0; h < H; ++h) {
                float sc = lrelu(as_[(size_t)s * H + h] + uad[h]);
                psum[h] += act ? __expf(sc) : 0.f;
            }
        }
        float inv[H];
#pragma unroll
        for (int h = 0; h < H; ++h)
            inv[h] = __builtin_amdgcn_rcpf(wred_sum(psum[h]) + 1e-16f);
        for (int base = r0; base < r1; base += 64) {
            int i = base + lane;
            bool act = i < r1;
            int se = act ? srcs[i] : 0;
            float ax[H];
#pragma unroll
            for (int h = 0; h < H; ++h) {
                float sc = lrelu(as_[(size_t)se * H + h] + uad[h]);
                ax[h] = act ? __expf(sc) * inv[h] : 0.f;
            }
            int cntc = min(64, r1 - base);
            unsigned off = (unsigned)(se * (RW * 4));
            sent[wid][lane] = make_uint4(off, __float_as_uint(ax[0]),
                                         off, __float_as_uint(ax[H - 1]));
            __threadfence_block();
            for (int t = 0; t < cntc; t += G) {
                uint2 en = *(const uint2*)(sbase + 4 * (t + grp));
                float af = __uint_as_float(en.y);
                const char* rowp = hflb + en.x;
                uint4 u0 = *(const uint4*)(rowp);
                f32x2 c;
                c.x = bf16lo(u0.x); c.y = bf16hi(u0.x); A[0] += af * c;
                c.x = bf16lo(u0.y); c.y = bf16hi(u0.y); A[1] += af * c;
                c.x = bf16lo(u0.z); c.y = bf16hi(u0.z); A[2] += af * c;
                c.x = bf16lo(u0.w); c.y = bf16hi(u0.w); A[3] += af * c;
                if (H == 2) {
                    uint4 u1 = *(const uint4*)(rowp + 16);
                    c.x = bf16lo(u1.x); c.y = bf16hi(u1.x); A[4] += af * c;
                    c.x = bf16lo(u1.y); c.y = bf16hi(u1.y); A[5] += af * c;
                    c.x = bf16lo(u1.z); c.y = bf16hi(u1.z); A[6] += af * c;
                    c.x = bf16lo(u1.w); c.y = bf16hi(u1.w); A[7] += af * c;
                }
            }
            __threadfence_block();
        }
    }

    // cross-group reduction (8 -> 1)
#pragma unroll
    for (int o = 8; o < 64; o <<= 1) {
#pragma unroll
        for (int q = 0; q < NV; ++q) {
            A[q].x += __shfl_xor(A[q].x, o);
            A[q].y += __shfl_xor(A[q].y, o);
        }
    }
    if (grp == 0) {
        int c0 = 8 * H * il;               // first channel this lane owns
        float v[2 * NV];
#pragma unroll
        for (int q = 0; q < NV; ++q) {
            float2 bq = *(const float2*)(bias + c0 + 2 * q);
            v[2 * q]     = A[q].x + bq.x;
            v[2 * q + 1] = A[q].y + bq.y;
        }
        if (DO_ELU) {
#pragma unroll
            for (int q = 0; q < 2 * NV; ++q) v[q] = v[q] > 0.f ? v[q] : expm1f(v[q]);
        }
        if (H == 2) {
            uint4 o1, o2;
            o1.x = pkbf(v[0], v[1]);  o1.y = pkbf(v[2], v[3]);
            o1.z = pkbf(v[4], v[5]);  o1.w = pkbf(v[6], v[7]);
            o2.x = pkbf(v[8], v[9]);  o2.y = pkbf(v[10], v[11]);
            o2.z = pkbf(v[12], v[13]); o2.w = pkbf(v[14], v[15]);
            unsigned* ob = (unsigned*)outp + (size_t)d * 64 + 8 * il;
            *(uint4*)ob = o1;
            *(uint4*)(ob + 4) = o2;
        } else {
            float* ob = (float*)outp + (size_t)d * 64 + c0;
            *(float4*)ob = make_float4(v[0], v[1], v[2], v[3]);
            *(float4*)(ob + 4) = make_float4(v[4], v[5], v[6], v[7]);
        }
    }
}

extern "C" void kernel_launch(void* const* d_in, const int* in_sizes, int n_in,
                              void* d_out, int out_size, void* d_ws, size_t ws_size,
                              hipStream_t stream) {
    const float* x   = (const float*)d_in[0];
    const int*   ei  = (const int*)d_in[1];
    const float* W1  = (const float*)d_in[2];
    const float* a1s = (const float*)d_in[3];
    const float* a1d = (const float*)d_in[4];
    const float* b1  = (const float*)d_in[5];
    const float* W2  = (const float*)d_in[6];
    const float* a2s = (const float*)d_in[7];
    const float* a2d = (const float*)d_in[8];
    const float* b2  = (const float*)d_in[9];
    float* out = (float*)d_out;

    int N  = in_sizes[0] / 128;
    int E  = in_sizes[1] / 2;
    int Et = E + N;
    int NB = (Et + 4095) / 4096;           // phase-1 blocks
    int nh = 256 * NB;                      // histogram entries

    char* p = (char*)d_ws;
    unsigned short* h1b = (unsigned short*)p;   p += (size_t)N * 128 * 2;
    unsigned short* act1b = (unsigned short*)p; p += (size_t)N * 128 * 2;
    unsigned short* h2b = (unsigned short*)p;   p += (size_t)N * 64 * 2;
    unsigned short* w1b = (unsigned short*)p;   p += 128 * 128 * 2;
    unsigned short* w2b = (unsigned short*)p;   p += 64 * 128 * 2;
    unsigned* tmp = (unsigned*)p;          p += (size_t)Et * 4;
    int* g_hist = (int*)p;                 p += (size_t)nh * 4;
    int* g_scan = (int*)p;                 p += (size_t)(nh + 1) * 4;
    int* partial = (int*)p;                p += (size_t)((nh + 255) / 256) * 4;
    float* as1 = (float*)p;                p += (size_t)N * 2 * 4;
    float* ad1 = (float*)p;                p += (size_t)N * 2 * 4;
    float* as2 = (float*)p;                p += (size_t)N * 4;
    float* ad2 = (float*)p;                p += (size_t)N * 4;
    int* rowptr = (int*)p;                 p += (size_t)(N + 1) * 4;
    int* srcs = (int*)p;                   p += (size_t)Et * 4;

    // ---- CSR build (packed u32 edges; no global atomics) ----
    int nbs = (nh + 255) / 256;
    k1_hist<<<NB + 12, 256, 0, stream>>>(ei, E, Et, g_hist, NB, W1, W2, w1b, w2b);
    scan_p1<<<nbs, 256, 0, stream>>>(g_hist, partial, nh);
    scan_p2<<<1, 256, 0, stream>>>(partial, nbs);
    scan_p3g<<<nbs, 256, 0, stream>>>(g_hist, partial, g_scan, nh);
    k3_scatter<<<NB, 256, 0, stream>>>(ei, E, Et, g_scan, tmp, NB);
    csr_finalize<<<256, 256, 0, stream>>>(tmp, g_scan, srcs, rowptr, N, Et, NB);

    // ---- layer 1 (x cast fused into GEMM) ----
    gemm_mfma<128, 2, true><<<(N + 63) / 64, 256, 0, stream>>>(x, w1b, a1s, a1d, h1b, as1, ad1, N);
    gat_agg<2, true><<<(N + 3) / 4, 256, 0, stream>>>(rowptr, srcs, as1, ad1,
                                                      (const unsigned*)h1b, b1, act1b, N);

    // ---- layer 2 ----
    gemm_mfma<64, 1, false><<<(N + 63) / 64, 256, 0, stream>>>(act1b, w2b, a2s, a2d, h2b, as2, ad2, N);
    gat_agg<1, false><<<(N + 3) / 4, 256, 0, stream>>>(rowptr, srcs, as2, ad2,
                                                       (const unsigned*)h2b, b2, out, N);
}

// Round 14
// 127.051 us; speedup vs baseline: 1.2154x; 1.2154x over previous
//
#include <hip/hip_runtime.h>
#include <hip/hip_bf16.h>
#include <math.h>

typedef __bf16 bf16x8 __attribute__((ext_vector_type(8)));
typedef float f32x4 __attribute__((ext_vector_type(4)));
typedef float f32x2 __attribute__((ext_vector_type(2)));

__device__ __forceinline__ float lrelu(float x) { return x > 0.f ? x : 0.2f * x; }
__device__ __forceinline__ unsigned short f2bf(float f) {
    unsigned u = __float_as_uint(f);
    return (unsigned short)((u + 0x7fffu + ((u >> 16) & 1u)) >> 16);
}
__device__ __forceinline__ float bf16lo(unsigned u) { return __uint_as_float(u << 16); }
__device__ __forceinline__ float bf16hi(unsigned u) { return __uint_as_float(u & 0xffff0000u); }
__device__ __forceinline__ unsigned pkbf(float a, float b) {
    return (unsigned)f2bf(a) | ((unsigned)f2bf(b) << 16);
}
__device__ __forceinline__ float wred_sum(float v) {
#pragma unroll
    for (int o = 32; o; o >>= 1) v += __shfl_xor(v, o);
    return v;
}

// ============ CSR build: two-level bucket sort on u32-packed edges (N < 65536) ========
// packed edge = (dst << 16) | src. coarse digit = dst>>8 = packed>>24.

// k1: per-block LDS histogram; tail blocks (b >= NB) cast W1/W2 to bf16.
__global__ __launch_bounds__(256) void k1_hist(const int* __restrict__ ei, int E, int Et,
                                               int* __restrict__ g_hist, int NB,
                                               const float* __restrict__ W1,
                                               const float* __restrict__ W2,
                                               unsigned short* __restrict__ w1b,
                                               unsigned short* __restrict__ w2b) {
    int tid = threadIdx.x, b = blockIdx.x;
    if (b >= NB) {
        int i = (b - NB) * 256 + tid;   // vec8 index
        const float* src;
        unsigned short* dst;
        size_t off;
        if (i < 2048)      { src = W1; dst = w1b; off = (size_t)i * 8; }
        else if (i < 3072) { src = W2; dst = w2b; off = (size_t)(i - 2048) * 8; }
        else return;
        float4 v0 = *(const float4*)(src + off);
        float4 v1 = *(const float4*)(src + off + 4);
        union { unsigned short u[8]; uint4 q; } o;
        o.u[0] = f2bf(v0.x); o.u[1] = f2bf(v0.y); o.u[2] = f2bf(v0.z); o.u[3] = f2bf(v0.w);
        o.u[4] = f2bf(v1.x); o.u[5] = f2bf(v1.y); o.u[6] = f2bf(v1.z); o.u[7] = f2bf(v1.w);
        *(uint4*)(dst + off) = o.q;
        return;
    }
    __shared__ int hist[256];
    hist[tid] = 0;
    __syncthreads();
    int base = b * 4096;
#pragma unroll
    for (int k = 0; k < 16; ++k) {
        int e = base + k * 256 + tid;
        if (e < Et) {
            int d = (e < E) ? ei[E + e] : (e - E);
            atomicAdd(&hist[d >> 8], 1);
        }
    }
    __syncthreads();
    g_hist[tid * NB + b] = hist[tid];
}

__global__ __launch_bounds__(256) void scan_p1(const int* __restrict__ in,
                                               int* __restrict__ partial, int n) {
    __shared__ int ws[4];
    int tid = threadIdx.x, lane = tid & 63, w = tid >> 6;
    int idx = blockIdx.x * 256 + tid;
    int v = (idx < n) ? in[idx] : 0;
    int s = v;
#pragma unroll
    for (int o = 32; o; o >>= 1) s += __shfl_xor(s, o);
    if (lane == 0) ws[w] = s;
    __syncthreads();
    if (tid == 0) partial[blockIdx.x] = ws[0] + ws[1] + ws[2] + ws[3];
}

__global__ __launch_bounds__(256) void scan_p2(int* __restrict__ partial, int nb) {
    __shared__ int ws[4];
    __shared__ int s_carry;
    int tid = threadIdx.x, lane = tid & 63, w = tid >> 6;
    if (tid == 0) s_carry = 0;
    __syncthreads();
    for (int base = 0; base < nb; base += 256) {
        int idx = base + tid;
        int v = (idx < nb) ? partial[idx] : 0;
        int incl = v;
#pragma unroll
        for (int off = 1; off < 64; off <<= 1) {
            int t = __shfl_up(incl, off);
            if (lane >= off) incl += t;
        }
        if (lane == 63) ws[w] = incl;
        __syncthreads();
        int wpre = 0;
        for (int k = 0; k < w; ++k) wpre += ws[k];
        int carry = s_carry;
        if (idx < nb) partial[idx] = carry + wpre + incl - v;
        __syncthreads();
        if (tid == 255) s_carry = carry + wpre + incl;
        __syncthreads();
    }
}

__global__ __launch_bounds__(256) void scan_p3g(const int* __restrict__ in,
                                                const int* __restrict__ partial,
                                                int* __restrict__ out, int n) {
    __shared__ int ws[4];
    int tid = threadIdx.x, lane = tid & 63, w = tid >> 6;
    int idx = blockIdx.x * 256 + tid;
    int v = (idx < n) ? in[idx] : 0;
    int incl = v;
#pragma unroll
    for (int off = 1; off < 64; off <<= 1) {
        int t = __shfl_up(incl, off);
        if (lane >= off) incl += t;
    }
    if (lane == 63) ws[w] = incl;
    __syncthreads();
    int wpre = 0;
    for (int k = 0; k < w; ++k) wpre += ws[k];
    if (idx < n) out[idx] = partial[blockIdx.x] + wpre + incl - v;
    if (idx == n - 1) out[n] = partial[blockIdx.x] + wpre + incl;
}

// k3_scatter fused with gemm1 (M=128, H=2, AF32): blocks [0,NB) scatter, rest gemm.
__global__ __launch_bounds__(256) void k3_gemm1(const int* __restrict__ ei, int E, int Et,
                                                const int* __restrict__ g_scan,
                                                unsigned* __restrict__ tmp, int NB,
                                                const float* __restrict__ x,
                                                const unsigned short* __restrict__ Wb,
                                                const float* __restrict__ att_s,
                                                const float* __restrict__ att_d,
                                                unsigned short* __restrict__ Cb,
                                                float* __restrict__ as_,
                                                float* __restrict__ ad_,
                                                int N) {
    int tid = threadIdx.x;
    if (blockIdx.x >= NB) {
        // ---- gemm1: C[N,128] = bf16(x) @ W1^T, + node_alpha ----
        constexpr int CT = 8;
        int wid = tid >> 6, l = tid & 63;
        int l15 = l & 15, lhi = l >> 4;
        int rowbase = (blockIdx.x - NB) * 64 + wid * 16;
        f32x4 acc[CT] = {};
        int rc = min(rowbase + l15, N - 1);
        const float* apf = x + (size_t)rc * 128 + lhi * 8;
        const unsigned short* wp = Wb + (size_t)l15 * 128 + lhi * 8;
#pragma unroll
        for (int ks = 0; ks < 4; ++ks) {
            int k0 = ks * 32;
            float4 u0 = *(const float4*)(apf + k0);
            float4 u1 = *(const float4*)(apf + k0 + 4);
            union { unsigned short s[8]; bf16x8 v; } cc;
            cc.s[0] = f2bf(u0.x); cc.s[1] = f2bf(u0.y); cc.s[2] = f2bf(u0.z); cc.s[3] = f2bf(u0.w);
            cc.s[4] = f2bf(u1.x); cc.s[5] = f2bf(u1.y); cc.s[6] = f2bf(u1.z); cc.s[7] = f2bf(u1.w);
            bf16x8 a = cc.v;
#pragma unroll
            for (int ct = 0; ct < CT; ++ct) {
                bf16x8 b = *reinterpret_cast<const bf16x8*>(wp + (size_t)ct * 16 * 128 + k0);
                acc[ct] = __builtin_amdgcn_mfma_f32_16x16x32_bf16(a, b, acc[ct], 0, 0, 0);
            }
        }
        int rbase = rowbase + lhi * 4;
#pragma unroll
        for (int j = 0; j < 4; ++j) {
            int gr = rbase + j;
            if (gr < N) {
#pragma unroll
                for (int ct = 0; ct < CT; ++ct)
                    Cb[(size_t)gr * 128 + ct * 16 + l15] = f2bf(acc[ct][j]);
            }
        }
#pragma unroll
        for (int hd = 0; hd < 2; ++hd) {
            float ps0 = 0.f, ps1 = 0.f, ps2 = 0.f, ps3 = 0.f;
            float pd0 = 0.f, pd1 = 0.f, pd2 = 0.f, pd3 = 0.f;
#pragma unroll
            for (int c4 = 0; c4 < 4; ++c4) {
                int ct = hd * 4 + c4;
                float ws = att_s[hd * 64 + c4 * 16 + l15];
                float wd = att_d[hd * 64 + c4 * 16 + l15];
                ps0 += acc[ct][0] * ws; pd0 += acc[ct][0] * wd;
                ps1 += acc[ct][1] * ws; pd1 += acc[ct][1] * wd;
                ps2 += acc[ct][2] * ws; pd2 += acc[ct][2] * wd;
                ps3 += acc[ct][3] * ws; pd3 += acc[ct][3] * wd;
            }
#pragma unroll
            for (int o = 1; o < 16; o <<= 1) {
                ps0 += __shfl_xor(ps0, o); pd0 += __shfl_xor(pd0, o);
                ps1 += __shfl_xor(ps1, o); pd1 += __shfl_xor(pd1, o);
                ps2 += __shfl_xor(ps2, o); pd2 += __shfl_xor(pd2, o);
                ps3 += __shfl_xor(ps3, o); pd3 += __shfl_xor(pd3, o);
            }
            if (l15 == 0) {
                int gr = rbase;
                if (gr < N)     { as_[(size_t)gr * 2 + hd] = ps0; ad_[(size_t)gr * 2 + hd] = pd0; }
                if (gr + 1 < N) { as_[(size_t)(gr + 1) * 2 + hd] = ps1; ad_[(size_t)(gr + 1) * 2 + hd] = pd1; }
                if (gr + 2 < N) { as_[(size_t)(gr + 2) * 2 + hd] = ps2; ad_[(size_t)(gr + 2) * 2 + hd] = pd2; }
                if (gr + 3 < N) { as_[(size_t)(gr + 3) * 2 + hd] = ps3; ad_[(size_t)(gr + 3) * 2 + hd] = pd3; }
            }
        }
        return;
    }
    // ---- scatter ----
    __shared__ int hist[256], lofs[256], lcnt[256], gbase[256];
    __shared__ int ws4[4];
    __shared__ unsigned stage[4096];
    int b = blockIdx.x;
    int lane = tid & 63, w = tid >> 6;
    int base = b * 4096;
    int valid = min(4096, Et - base);
    unsigned pv[16];
    hist[tid] = 0;
    lcnt[tid] = 0;
    gbase[tid] = g_scan[tid * NB + b];
    __syncthreads();
#pragma unroll
    for (int k = 0; k < 16; ++k) {
        int e = base + k * 256 + tid;
        if (e < Et) {
            int s, d;
            if (e < E) { s = ei[e]; d = ei[E + e]; } else { s = d = e - E; }
            pv[k] = ((unsigned)d << 16) | (unsigned)s;
            atomicAdd(&hist[d >> 8], 1);
        }
    }
    __syncthreads();
    {
        int v = hist[tid];
        int incl = v;
#pragma unroll
        for (int off = 1; off < 64; off <<= 1) {
            int t = __shfl_up(incl, off);
            if (lane >= off) incl += t;
        }
        if (lane == 63) ws4[w] = incl;
        __syncthreads();
        int wpre = 0;
        for (int k = 0; k < w; ++k) wpre += ws4[k];
        lofs[tid] = wpre + incl - v;
    }
    __syncthreads();
#pragma unroll
    for (int k = 0; k < 16; ++k) {
        int e = base + k * 256 + tid;
        if (e < Et) {
            int dg = pv[k] >> 24;
            int r = atomicAdd(&lcnt[dg], 1);
            stage[lofs[dg] + r] = pv[k];
        }
    }
    __syncthreads();
    for (int j = tid; j < valid; j += 256) {
        unsigned v = stage[j];
        int dg = v >> 24;
        tmp[gbase[dg] + (j - lofs[dg])] = v;
    }
}

__global__ __launch_bounds__(256) void csr_finalize(const unsigned* __restrict__ tmp,
                                                    const int* __restrict__ g_scan,
                                                    int* __restrict__ srcs,
                                                    int* __restrict__ rowptr,
                                                    int N, int Et, int NB) {
    __shared__ int cnt[256], lofs[256], lcnt[256];
    __shared__ int ws4[4];
    __shared__ unsigned short sstage[8192];
    int tid = threadIdx.x, g = blockIdx.x;
    int lane = tid & 63, w = tid >> 6;
    int start = g_scan[g * NB];
    int end = g_scan[(g + 1) * NB];
    int sz = end - start;
    cnt[tid] = 0;
    lcnt[tid] = 0;
    __syncthreads();
    for (int e = start + tid; e < end; e += 256)
        atomicAdd(&cnt[(tmp[e] >> 16) & 255u], 1);
    __syncthreads();
    {
        int v = cnt[tid];
        int incl = v;
#pragma unroll
        for (int off = 1; off < 64; off <<= 1) {
            int t = __shfl_up(incl, off);
            if (lane >= off) incl += t;
        }
        if (lane == 63) ws4[w] = incl;
        __syncthreads();
        int wpre = 0;
        for (int k = 0; k < w; ++k) wpre += ws4[k];
        lofs[tid] = wpre + incl - v;
    }
    __syncthreads();
    int d = g * 256 + tid;
    if (d < N) rowptr[d] = start + lofs[tid];
    if (d == N - 1) rowptr[N] = Et;
    if (sz <= 8192) {
        for (int e = start + tid; e < end; e += 256) {
            unsigned v = tmp[e];
            int sub = (v >> 16) & 255u;
            int pos = lofs[sub] + atomicAdd(&lcnt[sub], 1);
            sstage[pos] = (unsigned short)(v & 0xffffu);
        }
        __syncthreads();
        for (int j = tid; j < sz; j += 256)
            srcs[start + j] = (int)sstage[j];
    } else {
        for (int e = start + tid; e < end; e += 256) {
            unsigned v = tmp[e];
            int sub = (v >> 16) & 255u;
            int pos = start + lofs[sub] + atomicAdd(&lcnt[sub], 1);
            srcs[pos] = (int)(v & 0xffffu);
        }
    }
}

// ------- MFMA GEMM (bf16 out) + fused node_alpha (layer 2) ------
template<int M, int H>
__global__ __launch_bounds__(256) void gemm_mfma(const unsigned short* __restrict__ Ab,
                                                 const unsigned short* __restrict__ Wb,
                                                 const float* __restrict__ att_s,
                                                 const float* __restrict__ att_d,
                                                 unsigned short* __restrict__ Cb,
                                                 float* __restrict__ as_,
                                                 float* __restrict__ ad_,
                                                 int N) {
    constexpr int CT = M / 16;
    int tid = threadIdx.x;
    int wid = tid >> 6, l = tid & 63;
    int l15 = l & 15, lhi = l >> 4;
    int rowbase = blockIdx.x * 64 + wid * 16;
    f32x4 acc[CT] = {};

    int rc = min(rowbase + l15, N - 1);
    const unsigned short* ap = Ab + (size_t)rc * 128 + lhi * 8;
    const unsigned short* wp = Wb + (size_t)l15 * 128 + lhi * 8;

#pragma unroll
    for (int ks = 0; ks < 4; ++ks) {
        int k0 = ks * 32;
        bf16x8 a = *reinterpret_cast<const bf16x8*>(ap + k0);
#pragma unroll
        for (int ct = 0; ct < CT; ++ct) {
            bf16x8 b = *reinterpret_cast<const bf16x8*>(wp + (size_t)ct * 16 * 128 + k0);
            acc[ct] = __builtin_amdgcn_mfma_f32_16x16x32_bf16(a, b, acc[ct], 0, 0, 0);
        }
    }

    int rbase = rowbase + lhi * 4;
#pragma unroll
    for (int j = 0; j < 4; ++j) {
        int gr = rbase + j;
        if (gr < N) {
#pragma unroll
            for (int ct = 0; ct < CT; ++ct)
                Cb[(size_t)gr * M + ct * 16 + l15] = f2bf(acc[ct][j]);
        }
    }
#pragma unroll
    for (int hd = 0; hd < H; ++hd) {
        float ps0 = 0.f, ps1 = 0.f, ps2 = 0.f, ps3 = 0.f;
        float pd0 = 0.f, pd1 = 0.f, pd2 = 0.f, pd3 = 0.f;
#pragma unroll
        for (int c4 = 0; c4 < 4; ++c4) {
            int ct = hd * 4 + c4;
            float ws = att_s[hd * 64 + c4 * 16 + l15];
            float wd = att_d[hd * 64 + c4 * 16 + l15];
            ps0 += acc[ct][0] * ws; pd0 += acc[ct][0] * wd;
            ps1 += acc[ct][1] * ws; pd1 += acc[ct][1] * wd;
            ps2 += acc[ct][2] * ws; pd2 += acc[ct][2] * wd;
            ps3 += acc[ct][3] * ws; pd3 += acc[ct][3] * wd;
        }
#pragma unroll
        for (int o = 1; o < 16; o <<= 1) {
            ps0 += __shfl_xor(ps0, o); pd0 += __shfl_xor(pd0, o);
            ps1 += __shfl_xor(ps1, o); pd1 += __shfl_xor(pd1, o);
            ps2 += __shfl_xor(ps2, o); pd2 += __shfl_xor(pd2, o);
            ps3 += __shfl_xor(ps3, o); pd3 += __shfl_xor(pd3, o);
        }
        if (l15 == 0) {
            int gr = rbase;
            if (gr < N)     { as_[(size_t)gr * H + hd] = ps0; ad_[(size_t)gr * H + hd] = pd0; }
            if (gr + 1 < N) { as_[(size_t)(gr + 1) * H + hd] = ps1; ad_[(size_t)(gr + 1) * H + hd] = pd1; }
            if (gr + 2 < N) { as_[(size_t)(gr + 2) * H + hd] = ps2; ad_[(size_t)(gr + 2) * H + hd] = pd2; }
            if (gr + 3 < N) { as_[(size_t)(gr + 3) * H + hd] = ps3; ad_[(size_t)(gr + 3) * H + hd] = pd3; }
        }
    }
}

// ------- fused softmax + aggregation (round-11 proven shape) ---
// H=2: 16 lanes/edge, 4 edges/iter, uint4 loads (8 ch/lane), bf16 out.
// H=1: 8 lanes/edge, 8 edges/iter, uint4 loads (8 ch/lane), f32 out.
template<int H, bool DO_ELU>
__global__ __launch_bounds__(256) void gat_agg(const int* __restrict__ rowptr,
                                               const int* __restrict__ srcs,
                                               const float* __restrict__ as_,
                                               const float* __restrict__ ad_,
                                               const unsigned* __restrict__ hfeat,
                                               const float* __restrict__ bias,
                                               void* __restrict__ outp, int N) {
    constexpr int RW = 32 * H;            // u32 words per feature row
    constexpr int G  = (H == 2) ? 4 : 8;  // edges per iteration
    constexpr int GL = 64 / G;            // lanes per edge
    __shared__ uint4 sent[4][64];
    int wid = threadIdx.x >> 6, lane = threadIdx.x & 63;
    int il = lane & (GL - 1);
    int grp = lane >> ((H == 2) ? 4 : 3);
    int d = blockIdx.x * 4 + wid;
    if (d >= N) return;
    int r0 = rowptr[d], r1 = rowptr[d + 1];
    int cnt = r1 - r0;
    float uad[H];
    if (H == 2) {
        float2 adp = *(const float2*)(ad_ + 2 * (size_t)d);
        uad[0] = adp.x; uad[H - 1] = adp.y;
    } else {
        uad[0] = ad_[d];
    }
    f32x2 A01 = {0.f, 0.f}, A23 = {0.f, 0.f}, A45 = {0.f, 0.f}, A67 = {0.f, 0.f};
    const char* hflb = (const char*)hfeat + 16 * il;   // lane-fixed byte offset
    bool hhi = (H == 2) && (il >= 8);
    const unsigned* sbase = reinterpret_cast<const unsigned*>(&sent[wid][0]) + (hhi ? 2 : 0);

    if (cnt <= 64) {
        int i = r0 + lane;
        bool act = i < r1;
        int se = act ? srcs[i] : 0;
        float ax[H];
        if (H == 2) {
            float2 asp = *(const float2*)(as_ + 2 * (size_t)se);
            float ex0 = act ? __expf(lrelu(asp.x + uad[0])) : 0.f;
            float ex1 = act ? __expf(lrelu(asp.y + uad[1])) : 0.f;
            float den0 = wred_sum(ex0);
            float den1 = wred_sum(ex1);
            ax[0] = ex0 * __builtin_amdgcn_rcpf(den0 + 1e-16f);
            ax[H - 1] = ex1 * __builtin_amdgcn_rcpf(den1 + 1e-16f);
        } else {
            float ex = act ? __expf(lrelu(as_[se] + uad[0])) : 0.f;
            float den = wred_sum(ex);
            ax[0] = ex * __builtin_amdgcn_rcpf(den + 1e-16f);
        }
        unsigned off = (unsigned)(se * (RW * 4));
        sent[wid][lane] = make_uint4(off, __float_as_uint(ax[0]),
                                     off, __float_as_uint(ax[H - 1]));
        __threadfence_block();
#pragma unroll 2
        for (int t = 0; t < cnt; t += G) {
            uint2 en = *(const uint2*)(sbase + 4 * (t + grp));
            float af = __uint_as_float(en.y);
            uint4 u = *(const uint4*)(hflb + en.x);
            f32x2 c;
            c.x = bf16lo(u.x); c.y = bf16hi(u.x); A01 += af * c;
            c.x = bf16lo(u.y); c.y = bf16hi(u.y); A23 += af * c;
            c.x = bf16lo(u.z); c.y = bf16hi(u.z); A45 += af * c;
            c.x = bf16lo(u.w); c.y = bf16hi(u.w); A67 += af * c;
        }
    } else {
        // chunked path (deg > 64) -- statistically never, correctness only
        float psum[H];
#pragma unroll
        for (int h = 0; h < H; ++h) psum[h] = 0.f;
        for (int base = r0; base < r1; base += 64) {
            int i = base + lane;
            bool act = i < r1;
            int s = act ? srcs[i] : 0;
#pragma unroll
            for (int h = 0; h < H; ++h) {
                float sc = lrelu(as_[(size_t)s * H + h] + uad[h]);
                psum[h] += act ? __expf(sc) : 0.f;
            }
        }
        float inv[H];
#pragma unroll
        for (int h = 0; h < H; ++h)
            inv[h] = __builtin_amdgcn_rcpf(wred_sum(psum[h]) + 1e-16f);
        for (int base = r0; base < r1; base += 64) {
            int i = base + lane;
            bool act = i < r1;
            int se = act ? srcs[i] : 0;
            float ax[H];
#pragma unroll
            for (int h = 0; h < H; ++h) {
                float sc = lrelu(as_[(size_t)se * H + h] + uad[h]);
                ax[h] = act ? __expf(sc) * inv[h] : 0.f;
            }
            int cntc = min(64, r1 - base);
            unsigned off = (unsigned)(se * (RW * 4));
            sent[wid][lane] = make_uint4(off, __float_as_uint(ax[0]),
                                         off, __float_as_uint(ax[H - 1]));
            __threadfence_block();
            for (int t = 0; t < cntc; t += G) {
                uint2 en = *(const uint2*)(sbase + 4 * (t + grp));
                float af = __uint_as_float(en.y);
                uint4 u = *(const uint4*)(hflb + en.x);
                f32x2 c;
                c.x = bf16lo(u.x); c.y = bf16hi(u.x); A01 += af * c;
                c.x = bf16lo(u.y); c.y = bf16hi(u.y); A23 += af * c;
                c.x = bf16lo(u.z); c.y = bf16hi(u.z); A45 += af * c;
                c.x = bf16lo(u.w); c.y = bf16hi(u.w); A67 += af * c;
            }
            __threadfence_block();
        }
    }

    // cross-group reduction
#pragma unroll
    for (int o = GL; o < 64; o <<= 1) {
        A01.x += __shfl_xor(A01.x, o); A01.y += __shfl_xor(A01.y, o);
        A23.x += __shfl_xor(A23.x, o); A23.y += __shfl_xor(A23.y, o);
        A45.x += __shfl_xor(A45.x, o); A45.y += __shfl_xor(A45.y, o);
        A67.x += __shfl_xor(A67.x, o); A67.y += __shfl_xor(A67.y, o);
    }
    if (grp == 0) {
        int c0 = 8 * il;
        float4 bA = *(const float4*)(bias + c0);
        float4 bB = *(const float4*)(bias + c0 + 4);
        float v0 = A01.x + bA.x, v1 = A01.y + bA.y, v2 = A23.x + bA.z, v3 = A23.y + bA.w;
        float v4 = A45.x + bB.x, v5 = A45.y + bB.y, v6 = A67.x + bB.z, v7 = A67.y + bB.w;
        if (DO_ELU) {
            v0 = v0 > 0.f ? v0 : expm1f(v0); v1 = v1 > 0.f ? v1 : expm1f(v1);
            v2 = v2 > 0.f ? v2 : expm1f(v2); v3 = v3 > 0.f ? v3 : expm1f(v3);
            v4 = v4 > 0.f ? v4 : expm1f(v4); v5 = v5 > 0.f ? v5 : expm1f(v5);
            v6 = v6 > 0.f ? v6 : expm1f(v6); v7 = v7 > 0.f ? v7 : expm1f(v7);
        }
        if (H == 2) {
            uint4 o;
            o.x = pkbf(v0, v1); o.y = pkbf(v2, v3);
            o.z = pkbf(v4, v5); o.w = pkbf(v6, v7);
            *(uint4*)((unsigned*)outp + (size_t)d * 64 + 4 * il) = o;
        } else {
            *(float4*)((float*)outp + (size_t)d * 64 + c0) = make_float4(v0, v1, v2, v3);
            *(float4*)((float*)outp + (size_t)d * 64 + c0 + 4) = make_float4(v4, v5, v6, v7);
        }
    }
}

extern "C" void kernel_launch(void* const* d_in, const int* in_sizes, int n_in,
                              void* d_out, int out_size, void* d_ws, size_t ws_size,
                              hipStream_t stream) {
    const float* x   = (const float*)d_in[0];
    const int*   ei  = (const int*)d_in[1];
    const float* W1  = (const float*)d_in[2];
    const float* a1s = (const float*)d_in[3];
    const float* a1d = (const float*)d_in[4];
    const float* b1  = (const float*)d_in[5];
    const float* W2  = (const float*)d_in[6];
    const float* a2s = (const float*)d_in[7];
    const float* a2d = (const float*)d_in[8];
    const float* b2  = (const float*)d_in[9];
    float* out = (float*)d_out;

    int N  = in_sizes[0] / 128;
    int E  = in_sizes[1] / 2;
    int Et = E + N;
    int NB = (Et + 4095) / 4096;           // phase-1 blocks
    int nh = 256 * NB;                      // histogram entries

    char* p = (char*)d_ws;
    unsigned short* h1b = (unsigned short*)p;   p += (size_t)N * 128 * 2;
    unsigned short* act1b = (unsigned short*)p; p += (size_t)N * 128 * 2;
    unsigned short* h2b = (unsigned short*)p;   p += (size_t)N * 64 * 2;
    unsigned short* w1b = (unsigned short*)p;   p += 128 * 128 * 2;
    unsigned short* w2b = (unsigned short*)p;   p += 64 * 128 * 2;
    unsigned* tmp = (unsigned*)p;          p += (size_t)Et * 4;
    int* g_hist = (int*)p;                 p += (size_t)nh * 4;
    int* g_scan = (int*)p;                 p += (size_t)(nh + 1) * 4;
    int* partial = (int*)p;                p += (size_t)((nh + 255) / 256) * 4;
    float* as1 = (float*)p;                p += (size_t)N * 2 * 4;
    float* ad1 = (float*)p;                p += (size_t)N * 2 * 4;
    float* as2 = (float*)p;                p += (size_t)N * 4;
    float* ad2 = (float*)p;                p += (size_t)N * 4;
    int* rowptr = (int*)p;                 p += (size_t)(N + 1) * 4;
    int* srcs = (int*)p;                   p += (size_t)Et * 4;

    // ---- CSR build (packed u32 edges; gemm1 fused into scatter launch) ----
    int nbs = (nh + 255) / 256;
    int gemm1_blocks = (N + 63) / 64;
    k1_hist<<<NB + 12, 256, 0, stream>>>(ei, E, Et, g_hist, NB, W1, W2, w1b, w2b);
    scan_p1<<<nbs, 256, 0, stream>>>(g_hist, partial, nh);
    scan_p2<<<1, 256, 0, stream>>>(partial, nbs);
    scan_p3g<<<nbs, 256, 0, stream>>>(g_hist, partial, g_scan, nh);
    k3_gemm1<<<NB + gemm1_blocks, 256, 0, stream>>>(ei, E, Et, g_scan, tmp, NB,
                                                    x, w1b, a1s, a1d, h1b, as1, ad1, N);
    csr_finalize<<<256, 256, 0, stream>>>(tmp, g_scan, srcs, rowptr, N, Et, NB);

    // ---- layer 1 aggregation ----
    gat_agg<2, true><<<(N + 3) / 4, 256, 0, stream>>>(rowptr, srcs, as1, ad1,
                                                      (const unsigned*)h1b, b1, act1b, N);

    // ---- layer 2 ----
    gemm_mfma<64, 1><<<(N + 63) / 64, 256, 0, stream>>>(act1b, w2b, a2s, a2d, h2b, as2, ad2, N);
    gat_agg<1, false><<<(N + 3) / 4, 256, 0, stream>>>(rowptr, srcs, as2, ad2,
                                                       (const unsigned*)h2b, b2, out, N);
}